// Round 1
// baseline (1008.128 us; speedup 1.0000x reference)
//
#include <hip/hip_runtime.h>
#include <math.h>

// Problem constants
#define BATCH   8
#define QLEN    256
#define KLEN    2048
#define KDIM    512
#define ADIMC   512
#define NHEADS  4
#define DKH     128
#define CHUNKW  4

static constexpr float INV_SCALE = 0.04419417382415922f; // 1/sqrt(512)
static constexpr float EPSV = 1e-6f;

typedef __attribute__((ext_vector_type(8))) short bf16x8;
typedef __attribute__((ext_vector_type(4))) float f32x4;

__device__ __forceinline__ unsigned short f2bf(float f) {
    unsigned u = __builtin_bit_cast(unsigned, f);
    u += 0x7fffu + ((u >> 16) & 1u);   // round-to-nearest-even
    return (unsigned short)(u >> 16);
}

// Async global->LDS, 16 B per lane (wave-uniform base + lane*16 rule).
__device__ __forceinline__ void gload_lds16(const void* g, void* l) {
    __builtin_amdgcn_global_load_lds(
        (const __attribute__((address_space(1))) void*)g,
        (__attribute__((address_space(3))) void*)l, 16, 0, 0);
}

// ---------------------------------------------------------------------------
// Elementwise f32 -> bf16 cast (4 elems/thread)
// ---------------------------------------------------------------------------
__global__ __launch_bounds__(256) void cast_bf16(
    const float* __restrict__ x, unsigned short* __restrict__ y, int n4)
{
    int i = blockIdx.x * 256 + threadIdx.x;
    if (i < n4) {
        float4 v = ((const float4*)x)[i];
        ushort4 o;
        o.x = f2bf(v.x); o.y = f2bf(v.y); o.z = f2bf(v.z); o.w = f2bf(v.w);
        ((ushort4*)y)[i] = o;
    }
}

// ---------------------------------------------------------------------------
// Transpose-cast: W [512 x 512] (k-major rows) -> WT [512 x 512] bf16, WT[n][k]
// ---------------------------------------------------------------------------
__global__ __launch_bounds__(256) void transpose_cast(
    const float* __restrict__ W, unsigned short* __restrict__ WT)
{
    __shared__ float tile[32][33];
    const int tx = threadIdx.x;          // 0..31
    const int ty = threadIdx.y;          // 0..7
    const int k0 = blockIdx.y * 32, n0 = blockIdx.x * 32;
    #pragma unroll
    for (int i = 0; i < 32; i += 8)
        tile[ty + i][tx] = W[(size_t)(k0 + ty + i) * KDIM + n0 + tx];
    __syncthreads();
    #pragma unroll
    for (int i = 0; i < 32; i += 8)
        WT[(size_t)(n0 + ty + i) * KDIM + k0 + tx] = f2bf(tile[tx][ty + i]);
}

// ---------------------------------------------------------------------------
// Staged NT MFMA core: block computes 128x128 f32 tile of A[M,K] @ B[N,K]^T.
// 256 threads / 4 waves, each wave a 64x64 subtile.
// ---------------------------------------------------------------------------
template<int KSTEPS>
__device__ __forceinline__ void mfma_nt_staged(
    const unsigned short* __restrict__ A, const unsigned short* __restrict__ B,
    int lda, int ldb, int bm, int bn,
    unsigned short* AsLDS, unsigned short* BsLDS, f32x4 acc[4][4])
{
    const int t = threadIdx.x;
    const int wv = t >> 6, ln = t & 63;
    const int r = ln & 15, quad = ln >> 4;
    const int wm = (wv >> 1) * 64, wn = (wv & 1) * 64;
    const int srow = wv * 16 + (ln >> 2);
    const int scol = (ln & 3) * 8;

    for (int ks = 0; ks < KSTEPS; ++ks) {
        const int k0 = ks * 32;
        #pragma unroll
        for (int j = 0; j < 2; ++j) {
            gload_lds16(A + (size_t)(bm + j * 64 + srow) * lda + k0 + scol,
                        AsLDS + (size_t)(j * 64 + wv * 16) * 32);
            gload_lds16(B + (size_t)(bn + j * 64 + srow) * ldb + k0 + scol,
                        BsLDS + (size_t)(j * 64 + wv * 16) * 32);
        }
        __syncthreads();
        bf16x8 af[4], bg[4];
        #pragma unroll
        for (int f = 0; f < 4; ++f)
            af[f] = *(const bf16x8*)(AsLDS + (size_t)(wm + f * 16 + r) * 32 + quad * 8);
        #pragma unroll
        for (int f = 0; f < 4; ++f)
            bg[f] = *(const bf16x8*)(BsLDS + (size_t)(wn + f * 16 + r) * 32 + quad * 8);
        #pragma unroll
        for (int i = 0; i < 4; ++i)
            #pragma unroll
            for (int j2 = 0; j2 < 4; ++j2)
                acc[i][j2] = __builtin_amdgcn_mfma_f32_16x16x32_bf16(
                    af[i], bg[j2], acc[i][j2], 0, 0, 0);
        __syncthreads();
    }
}

__device__ __forceinline__ void zero_acc(f32x4 acc[4][4]) {
    #pragma unroll
    for (int i = 0; i < 4; ++i)
        #pragma unroll
        for (int j = 0; j < 4; ++j)
            acc[i][j] = f32x4{0.f, 0.f, 0.f, 0.f};
}

// ---------------------------------------------------------------------------
// Projection: C[M x 1024] bf16 = A[M x 512] @ WT[1024 x 512]^T + bias
// ---------------------------------------------------------------------------
__global__ __launch_bounds__(256) void proj_mfma(
    const unsigned short* __restrict__ A, const unsigned short* __restrict__ WT,
    const float* __restrict__ bias_m, const float* __restrict__ bias_c,
    unsigned short* __restrict__ C)
{
    __shared__ unsigned short As[128 * 32];
    __shared__ unsigned short Bs[128 * 32];
    const int bm = blockIdx.y * 128, bn = blockIdx.x * 128;
    f32x4 acc[4][4]; zero_acc(acc);
    mfma_nt_staged<16>(A, WT, KDIM, KDIM, bm, bn, As, Bs, acc);
    const int wv = threadIdx.x >> 6, ln = threadIdx.x & 63;
    const int r = ln & 15, quad = ln >> 4;
    const int m0 = bm + (wv >> 1) * 64, n0 = bn + (wv & 1) * 64;
    #pragma unroll
    for (int j = 0; j < 4; ++j) {
        const int n = n0 + j * 16 + r;
        const float bv = (n < 512) ? bias_m[n] : bias_c[n - 512];
        #pragma unroll
        for (int i = 0; i < 4; ++i) {
            #pragma unroll
            for (int reg = 0; reg < 4; ++reg) {
                const int m = m0 + i * 16 + quad * 4 + reg;
                C[(size_t)m * 1024 + n] = f2bf(acc[i][j][reg] + bv);
            }
        }
    }
}

// ---------------------------------------------------------------------------
// p_choose: per batch b, p = sigmoid(qm[b] @ km[b]^T / sqrt(512) + r + noise)
// ---------------------------------------------------------------------------
__global__ __launch_bounds__(256) void pchoose_mfma(
    const unsigned short* __restrict__ qp, const unsigned short* __restrict__ kp,
    const float* __restrict__ noise, const float* __restrict__ rp,
    float* __restrict__ p)
{
    __shared__ unsigned short As[128 * 32];
    __shared__ unsigned short Bs[128 * 32];
    const int b = blockIdx.z;
    const unsigned short* A = qp + (size_t)b * QLEN * 1024;
    const unsigned short* B = kp + (size_t)b * KLEN * 1024;
    const int bm = blockIdx.y * 128, bn = blockIdx.x * 128;
    f32x4 acc[4][4]; zero_acc(acc);
    mfma_nt_staged<16>(A, B, 1024, 1024, bm, bn, As, Bs, acc);
    const int wv = threadIdx.x >> 6, ln = threadIdx.x & 63;
    const int r = ln & 15, quad = ln >> 4;
    const int m0 = bm + (wv >> 1) * 64, n0 = bn + (wv & 1) * 64;
    const float rv = rp[0];
    #pragma unroll
    for (int i = 0; i < 4; ++i) {
        #pragma unroll
        for (int reg = 0; reg < 4; ++reg) {
            const int q = m0 + i * 16 + quad * 4 + reg;
            const size_t rowoff = ((size_t)b * QLEN + q) * KLEN;
            #pragma unroll
            for (int j = 0; j < 4; ++j) {
                const int k = n0 + j * 16 + r;
                const float e = acc[i][j][reg] * INV_SCALE + rv + noise[rowoff + k];
                p[rowoff + k] = __builtin_amdgcn_rcpf(1.0f + __expf(-e));
            }
        }
    }
}

// ---------------------------------------------------------------------------
// 64-lane inclusive prefix sum via DPP (≈6 VALU ops)
// ---------------------------------------------------------------------------
__device__ __forceinline__ float wave_incl_scan(float x)
{
#define DPP_ADD(ctrl, rmask, bctrl)                                            \
    { int _t = __builtin_amdgcn_update_dpp(0, __builtin_bit_cast(int, x),      \
                                           ctrl, rmask, 0xf, bctrl);           \
      x += __builtin_bit_cast(float, _t); }
    DPP_ADD(0x111, 0xf, true)   // row_shr:1
    DPP_ADD(0x112, 0xf, true)   // row_shr:2
    DPP_ADD(0x114, 0xf, true)   // row_shr:4
    DPP_ADD(0x118, 0xf, true)   // row_shr:8
    DPP_ADD(0x142, 0xa, false)  // row_bcast:15 -> rows 1,3
    DPP_ADD(0x143, 0xc, false)  // row_bcast:31 -> rows 2,3
#undef DPP_ADD
    return x;
}

// ---------------------------------------------------------------------------
// cumprod_mr: per (b,q) row: cp = exp(excl_cumsum(log(clip(1-p)))); emits
// m = p*cp, r = 1/clip(cp). Fast intrinsics; absorbs all transcendentals.
// ---------------------------------------------------------------------------
__global__ __launch_bounds__(256) void cumprod_mr(
    const float* __restrict__ p, float* __restrict__ mArr, float* __restrict__ rArr)
{
    const size_t row = blockIdx.x;
    const float* pr = p + row * KLEN;
    float* mr = mArr + row * KLEN;
    float* rr = rArr + row * KLEN;
    const int tid = threadIdx.x;
    const int lane = tid & 63, wid = tid >> 6;
    __shared__ float waveTot[4];

    float4 v0 = *(const float4*)(pr + tid * 8);
    float4 v1 = *(const float4*)(pr + tid * 8 + 4);
    float pv[8] = {v0.x, v0.y, v0.z, v0.w, v1.x, v1.y, v1.z, v1.w};
    float excl[8];
    float run = 0.0f;
    #pragma unroll
    for (int j = 0; j < 8; ++j) {
        float l = __logf(fminf(fmaxf(1.0f - pv[j], EPSV), 1.0f));
        excl[j] = run;
        run += l;
    }
    float s = wave_incl_scan(run);
    if (lane == 63) waveTot[wid] = s;
    __syncthreads();
    float wex = 0.0f;
    for (int w = 0; w < wid; ++w) wex += waveTot[w];
    const float texcl = wex + s - run;

    float mv[8], rv[8];
    #pragma unroll
    for (int j = 0; j < 8; ++j) {
        const float cpv = __expf(texcl + excl[j]);
        mv[j] = pv[j] * cpv;
        rv[j] = __builtin_amdgcn_rcpf(fminf(fmaxf(cpv, EPSV), 1.0f));
    }
    *(float4*)(mr + tid * 8)     = *(float4*)&mv[0];
    *(float4*)(mr + tid * 8 + 4) = *(float4*)&mv[4];
    *(float4*)(rr + tid * 8)     = *(float4*)&rv[0];
    *(float4*)(rr + tid * 8 + 4) = *(float4*)&rv[4];
}

// ---------------------------------------------------------------------------
// alpha_echunk: FUSED kernel.
//  Blocks 0..7: SINGLE-WAVE alpha recurrence. One wave handles a whole batch
//  row (32 elems/lane, 8 float4). No LDS, no barriers: the old 8-wave version
//  paid an LDS write + s_barrier + LDS read round-trip (~500 cyc) every one of
//  the 256 serial steps. Here the cross-klen prefix is: 4 independent in-lane
//  fmaf chains of 8 (prefix stored in-place into aw regs) + the 6-op DPP wave
//  scan. m/r double-buffered in registers; rc prefetch issues mid-step (rc
//  regs dead after the chain) for ~1.5-step latency cover.
//  Blocks 8..1031: e_chunk MFMA tiles (unchanged; fills the idle CUs).
// ---------------------------------------------------------------------------
__global__ __launch_bounds__(512, 1) void alpha_echunk(
    const float* __restrict__ mArr, const float* __restrict__ rArr,
    float* __restrict__ alpha,
    const unsigned short* __restrict__ qp, const unsigned short* __restrict__ kp,
    float* __restrict__ out)
{
    __shared__ __align__(16) char smem[16384];
    const int bid = blockIdx.x;
    const int tid = threadIdx.x;

    if (bid < BATCH) {
        // ---------------- single-wave alpha scan ----------------
        if (tid >= 64) return;           // waves 1..7 exit (no barrier here)
        const int l = tid;               // lane 0..63
        const size_t rowbase = (size_t)bid * QLEN * KLEN + (size_t)l * 32;
        const float* mb = mArr + rowbase;
        const float* rb = rArr + rowbase;
        float* ab = alpha + rowbase;

        float4 aw[8];
        #pragma unroll
        for (int j = 0; j < 8; ++j) aw[j] = float4{0.f, 0.f, 0.f, 0.f};
        if (l == 0) aw[0].x = 1.0f;      // one-hot at k=0

        float4 mA[8], rA[8], mB[8], rB[8];
        #pragma unroll
        for (int j = 0; j < 8; ++j) {
            mA[j] = *(const float4*)(mb + 4 * j);
            rA[j] = *(const float4*)(rb + 4 * j);
            mB[j] = *(const float4*)(mb + KLEN + 4 * j);
            rB[j] = *(const float4*)(rb + KLEN + 4 * j);
        }

// in-lane group chain: 8 elems (2 float4s), prefix written in place into aw
#define GRP(c, J0, J1, RC)                                                     \
        c = fmaf(aw[J0].x, RC[J0].x, c); aw[J0].x = c;                         \
        c = fmaf(aw[J0].y, RC[J0].y, c); aw[J0].y = c;                         \
        c = fmaf(aw[J0].z, RC[J0].z, c); aw[J0].z = c;                         \
        c = fmaf(aw[J0].w, RC[J0].w, c); aw[J0].w = c;                         \
        c = fmaf(aw[J1].x, RC[J1].x, c); aw[J1].x = c;                         \
        c = fmaf(aw[J1].y, RC[J1].y, c); aw[J1].y = c;                         \
        c = fmaf(aw[J1].z, RC[J1].z, c); aw[J1].z = c;                         \
        c = fmaf(aw[J1].w, RC[J1].w, c); aw[J1].w = c;

#define EPI(J0, J1, MC, Bg)                                                    \
        aw[J0].x = MC[J0].x * (Bg + aw[J0].x);                                 \
        aw[J0].y = MC[J0].y * (Bg + aw[J0].y);                                 \
        aw[J0].z = MC[J0].z * (Bg + aw[J0].z);                                 \
        aw[J0].w = MC[J0].w * (Bg + aw[J0].w);                                 \
        aw[J1].x = MC[J1].x * (Bg + aw[J1].x);                                 \
        aw[J1].y = MC[J1].y * (Bg + aw[J1].y);                                 \
        aw[J1].z = MC[J1].z * (Bg + aw[J1].z);                                 \
        aw[J1].w = MC[J1].w * (Bg + aw[J1].w);

#define A1(I, MC, RC)                                                          \
    {                                                                          \
        const int i_ = (I);                                                    \
        float t0 = 0.f, t1 = 0.f, t2 = 0.f, t3 = 0.f;                          \
        GRP(t0, 0, 1, RC)                                                      \
        GRP(t1, 2, 3, RC)                                                      \
        GRP(t2, 4, 5, RC)                                                      \
        GRP(t3, 6, 7, RC)                                                      \
        const float o1 = t0, o2 = o1 + t1, o3 = o2 + t2;                       \
        float run = o3 + t3;                                                   \
        /* rc regs dead -> prefetch r for step i+2 now (latency cover) */      \
        const int rn_ = (i_ + 2 < QLEN) ? (i_ + 2) : (QLEN - 1);               \
        const float* rbn = rb + (size_t)rn_ * KLEN;                            \
        RC[0] = *(const float4*)(rbn);                                         \
        RC[1] = *(const float4*)(rbn + 4);                                     \
        RC[2] = *(const float4*)(rbn + 8);                                     \
        RC[3] = *(const float4*)(rbn + 12);                                    \
        RC[4] = *(const float4*)(rbn + 16);                                    \
        RC[5] = *(const float4*)(rbn + 20);                                    \
        RC[6] = *(const float4*)(rbn + 24);                                    \
        RC[7] = *(const float4*)(rbn + 28);                                    \
        const float s_ = wave_incl_scan(run);                                  \
        const float base = s_ - run;                                           \
        const float B0 = base, B1 = base + o1, B2 = base + o2, B3 = base + o3; \
        EPI(0, 1, MC, B0)                                                      \
        EPI(2, 3, MC, B1)                                                      \
        EPI(4, 5, MC, B2)                                                      \
        EPI(6, 7, MC, B3)                                                      \
        float* ao = ab + (size_t)i_ * KLEN;                                    \
        *(float4*)(ao)      = aw[0];                                           \
        *(float4*)(ao + 4)  = aw[1];                                           \
        *(float4*)(ao + 8)  = aw[2];                                           \
        *(float4*)(ao + 12) = aw[3];                                           \
        *(float4*)(ao + 16) = aw[4];                                           \
        *(float4*)(ao + 20) = aw[5];                                           \
        *(float4*)(ao + 24) = aw[6];                                           \
        *(float4*)(ao + 28) = aw[7];                                           \
        /* mc regs dead -> prefetch m for step i+2 */                          \
        const float* mbn = mb + (size_t)rn_ * KLEN;                            \
        MC[0] = *(const float4*)(mbn);                                         \
        MC[1] = *(const float4*)(mbn + 4);                                     \
        MC[2] = *(const float4*)(mbn + 8);                                     \
        MC[3] = *(const float4*)(mbn + 12);                                    \
        MC[4] = *(const float4*)(mbn + 16);                                    \
        MC[5] = *(const float4*)(mbn + 20);                                    \
        MC[6] = *(const float4*)(mbn + 24);                                    \
        MC[7] = *(const float4*)(mbn + 28);                                    \
    }

        for (int io = 0; io < QLEN; io += 2) {
            A1(io + 0, mA, rA)
            A1(io + 1, mB, rB)
        }
#undef A1
#undef EPI
#undef GRP
        return;
    }

    // ---------------- echunk tile ----------------
    const int v = bid - BATCH;           // 0..1023
    const int z = v >> 5;                // 0..31 = b*4+h
    const int by = (v >> 4) & 1;
    const int bx = v & 15;
    const int b = z >> 2, h = z & 3;
    const bool worker = tid < 256;
    unsigned short* As = (unsigned short*)smem;            // 8 KB
    unsigned short* Bs = (unsigned short*)(smem + 8192);   // 8 KB
    const unsigned short* A = qp + (size_t)b * QLEN * 1024 + 512 + h * DKH;
    const unsigned short* B = kp + (size_t)b * KLEN * 1024 + 512 + h * DKH;
    const int bm = by * 128, bn = bx * 128;

    const int wv = tid >> 6, ln = tid & 63;
    const int r = ln & 15, quad = ln >> 4;
    const int wm = (wv >> 1) * 64, wn = (wv & 1) * 64;
    const int srow = (wv & 3) * 16 + (ln >> 2);
    const int scol = (ln & 3) * 8;

    f32x4 acc[4][4]; zero_acc(acc);
    for (int ks = 0; ks < 4; ++ks) {
        const int k0 = ks * 32;
        if (worker) {
            #pragma unroll
            for (int j = 0; j < 2; ++j) {
                gload_lds16(A + (size_t)(bm + j * 64 + srow) * 1024 + k0 + scol,
                            As + (size_t)(j * 64 + wv * 16) * 32);
                gload_lds16(B + (size_t)(bn + j * 64 + srow) * 1024 + k0 + scol,
                            Bs + (size_t)(j * 64 + wv * 16) * 32);
            }
        }
        __syncthreads();
        if (worker) {
            bf16x8 af[4], bg[4];
            #pragma unroll
            for (int f = 0; f < 4; ++f)
                af[f] = *(const bf16x8*)(As + (size_t)(wm + f * 16 + r) * 32 + quad * 8);
            #pragma unroll
            for (int f = 0; f < 4; ++f)
                bg[f] = *(const bf16x8*)(Bs + (size_t)(wn + f * 16 + r) * 32 + quad * 8);
            #pragma unroll
            for (int i = 0; i < 4; ++i)
                #pragma unroll
                for (int j2 = 0; j2 < 4; ++j2)
                    acc[i][j2] = __builtin_amdgcn_mfma_f32_16x16x32_bf16(
                        af[i], bg[j2], acc[i][j2], 0, 0, 0);
        }
        __syncthreads();
    }
    if (worker) {
        const int m0 = bm + (wv >> 1) * 64, n0 = bn + (wv & 1) * 64;
        #pragma unroll
        for (int i = 0; i < 4; ++i) {
            #pragma unroll
            for (int reg = 0; reg < 4; ++reg) {
                const int q = m0 + i * 16 + quad * 4 + reg;
                const size_t rowoff = ((size_t)z * QLEN + q) * KLEN;
                #pragma unroll
                for (int j = 0; j < 4; ++j) {
                    const int k = n0 + j * 16 + r;
                    out[rowoff + k] = acc[i][j][reg] * INV_SCALE;
                }
            }
        }
    }
}

// ---------------------------------------------------------------------------
// beta: per (b,h,q) row of 2048 (e_chunk in d_out, overwritten)
// ---------------------------------------------------------------------------
__global__ __launch_bounds__(256) void beta_kernel(
    float* __restrict__ eo, const float* __restrict__ alpha)
{
    __shared__ float sse[KLEN + 3];
    __shared__ float su[KLEN + 3];
    __shared__ float wmax[4];

    const int tid = threadIdx.x;
    const int lane = tid & 63, wid = tid >> 6;
    const int row = blockIdx.x;                 // [B*H*Q]
    const int q = row & (QLEN - 1);
    const int b = row >> 10;
    float* erow = eo + (size_t)row * KLEN;
    const float* arow = alpha + ((size_t)b * QLEN + q) * KLEN;

    if (tid < 3) { sse[tid] = 0.0f; su[KLEN + tid] = 0.0f; }

    float ev[8];
    float lm = -INFINITY;
    #pragma unroll
    for (int j = 0; j < 8; ++j) {
        const int k = tid + 256 * j;
        ev[j] = erow[k];
        lm = fmaxf(lm, ev[j]);
    }
    #pragma unroll
    for (int off = 32; off > 0; off >>= 1) lm = fmaxf(lm, __shfl_xor(lm, off));
    if (lane == 0) wmax[wid] = lm;
    __syncthreads();
    const float mx = fmaxf(fmaxf(wmax[0], wmax[1]), fmaxf(wmax[2], wmax[3]));

    #pragma unroll
    for (int j = 0; j < 8; ++j) {
        const int k = tid + 256 * j;
        sse[k + 3] = fmaxf(__expf(ev[j] - mx), 1e-5f);
    }
    __syncthreads();

    #pragma unroll
    for (int j = 0; j < 8; ++j) {
        const int k = tid + 256 * j;
        const float denom = sse[k + 3] + sse[k + 2] + sse[k + 1] + sse[k];
        su[k] = arow[k] * __builtin_amdgcn_rcpf(denom);
    }
    __syncthreads();

    #pragma unroll
    for (int j = 0; j < 8; ++j) {
        const int k = tid + 256 * j;
        erow[k] = sse[k + 3] * (su[k] + su[k + 1] + su[k + 2] + su[k + 3]);
    }
}

// ---------------------------------------------------------------------------
extern "C" void kernel_launch(void* const* d_in, const int* in_sizes, int n_in,
                              void* d_out, int out_size, void* d_ws, size_t ws_size,
                              hipStream_t stream)
{
    (void)in_sizes; (void)n_in; (void)out_size; (void)ws_size;
    const float* key_enc = (const float*)d_in[0];   // [8,2048,512]
    const float* query   = (const float*)d_in[1];   // [8,256,512]
    const float* noise   = (const float*)d_in[2];   // [8,256,2048]
    const float* Wk_m    = (const float*)d_in[3];
    const float* bk_m    = (const float*)d_in[4];
    const float* Wq_m    = (const float*)d_in[5];
    const float* bq_m    = (const float*)d_in[6];
    const float* rp      = (const float*)d_in[7];
    const float* Wk_c    = (const float*)d_in[8];
    const float* bk_c    = (const float*)d_in[9];
    const float* Wq_c    = (const float*)d_in[10];
    const float* bq_c    = (const float*)d_in[11];
    float* out = (float*)d_out;                     // [8,4,256,2048]

    // workspace layout (bytes)
    char* w = (char*)d_ws;
    unsigned short* kx    = (unsigned short*)w; w += (size_t)BATCH * KLEN * KDIM * 2;   // 16.8 MB
    unsigned short* qx    = (unsigned short*)w; w += (size_t)BATCH * QLEN * KDIM * 2;   //  2.1 MB
    unsigned short* WTk   = (unsigned short*)w; w += (size_t)1024 * KDIM * 2;           //  1.0 MB
    unsigned short* WTq   = (unsigned short*)w; w += (size_t)1024 * KDIM * 2;           //  1.0 MB
    unsigned short* kproj = (unsigned short*)w; w += (size_t)BATCH * KLEN * 1024 * 2;   // 33.6 MB
    unsigned short* qproj = (unsigned short*)w; w += (size_t)BATCH * QLEN * 1024 * 2;   //  4.2 MB
    float* p_alpha = (float*)w; w += (size_t)BATCH * QLEN * KLEN * 4;                   // 16.8 MB
    float* mArr    = (float*)w; w += (size_t)BATCH * QLEN * KLEN * 4;                   // 16.8 MB
    float* rArr    = (float*)w;                                                         // 16.8 MB

    // 1) casts
    hipLaunchKernelGGL(cast_bf16, dim3(BATCH * KLEN * KDIM / 4 / 256), dim3(256), 0, stream,
                       key_enc, kx, BATCH * KLEN * KDIM / 4);
    hipLaunchKernelGGL(cast_bf16, dim3(BATCH * QLEN * KDIM / 4 / 256), dim3(256), 0, stream,
                       query, qx, BATCH * QLEN * KDIM / 4);
    hipLaunchKernelGGL(transpose_cast, dim3(16, 16), dim3(32, 8), 0, stream, Wk_m, WTk);
    hipLaunchKernelGGL(transpose_cast, dim3(16, 16), dim3(32, 8), 0, stream, Wk_c, WTk + (size_t)512 * KDIM);
    hipLaunchKernelGGL(transpose_cast, dim3(16, 16), dim3(32, 8), 0, stream, Wq_m, WTq);
    hipLaunchKernelGGL(transpose_cast, dim3(16, 16), dim3(32, 8), 0, stream, Wq_c, WTq + (size_t)512 * KDIM);

    // 2) projections (staged bf16 MFMA, fused bias, bf16 out)
    hipLaunchKernelGGL(proj_mfma, dim3(8, BATCH * KLEN / 128), dim3(256), 0, stream,
                       kx, WTk, bk_m, bk_c, kproj);
    hipLaunchKernelGGL(proj_mfma, dim3(8, BATCH * QLEN / 128), dim3(256), 0, stream,
                       qx, WTq, bq_m, bq_c, qproj);

    // 3) p_choose (staged bf16 MFMA + fast sigmoid epilogue)
    hipLaunchKernelGGL(pchoose_mfma, dim3(KLEN / 128, QLEN / 128, BATCH), dim3(256), 0, stream,
                       qproj, kproj, noise, rp, p_alpha);

    // 4) cumprod -> (m, r)  (parallel, absorbs all transcendentals)
    hipLaunchKernelGGL(cumprod_mr, dim3(BATCH * QLEN), dim3(256), 0, stream,
                       p_alpha, mArr, rArr);

    // 5) FUSED: alpha recurrence (blocks 0..7, single-wave) + e_chunk (blocks 8..1031)
    hipLaunchKernelGGL(alpha_echunk, dim3(BATCH + KLEN / 128 * QLEN / 128 * BATCH * NHEADS),
                       dim3(512), 0, stream,
                       mArr, rArr, p_alpha, qproj, kproj, out);

    // 6) beta (overwrites e_chunk rows in d_out)
    hipLaunchKernelGGL(beta_kernel, dim3(BATCH * NHEADS * QLEN), dim3(256), 0, stream,
                       out, p_alpha);
}

// Round 2
// 470.336 us; speedup vs baseline: 2.1434x; 2.1434x over previous
//
#include <hip/hip_runtime.h>
#include <math.h>

// Problem constants
#define BATCH   8
#define QLEN    256
#define KLEN    2048
#define KDIM    512
#define ADIMC   512
#define NHEADS  4
#define DKH     128
#define CHUNKW  4

static constexpr float INV_SCALE = 0.04419417382415922f; // 1/sqrt(512)
static constexpr float EPSV = 1e-6f;

typedef __attribute__((ext_vector_type(8))) short bf16x8;
typedef __attribute__((ext_vector_type(4))) float f32x4;

__device__ __forceinline__ unsigned short f2bf(float f) {
    unsigned u = __builtin_bit_cast(unsigned, f);
    u += 0x7fffu + ((u >> 16) & 1u);   // round-to-nearest-even
    return (unsigned short)(u >> 16);
}

// Async global->LDS, 16 B per lane (wave-uniform LDS base + lane*16 rule;
// global source address is per-lane).
__device__ __forceinline__ void gload_lds16(const void* g, void* l) {
    __builtin_amdgcn_global_load_lds(
        (const __attribute__((address_space(1))) void*)g,
        (__attribute__((address_space(3))) void*)l, 16, 0, 0);
}

// ---------------------------------------------------------------------------
// Elementwise f32 -> bf16 cast (4 elems/thread)
// ---------------------------------------------------------------------------
__global__ __launch_bounds__(256) void cast_bf16(
    const float* __restrict__ x, unsigned short* __restrict__ y, int n4)
{
    int i = blockIdx.x * 256 + threadIdx.x;
    if (i < n4) {
        float4 v = ((const float4*)x)[i];
        ushort4 o;
        o.x = f2bf(v.x); o.y = f2bf(v.y); o.z = f2bf(v.z); o.w = f2bf(v.w);
        ((ushort4*)y)[i] = o;
    }
}

// ---------------------------------------------------------------------------
// Transpose-cast: W [512 x 512] (k-major rows) -> WT [512 x 512] bf16, WT[n][k]
// ---------------------------------------------------------------------------
__global__ __launch_bounds__(256) void transpose_cast(
    const float* __restrict__ W, unsigned short* __restrict__ WT)
{
    __shared__ float tile[32][33];
    const int tx = threadIdx.x;          // 0..31
    const int ty = threadIdx.y;          // 0..7
    const int k0 = blockIdx.y * 32, n0 = blockIdx.x * 32;
    #pragma unroll
    for (int i = 0; i < 32; i += 8)
        tile[ty + i][tx] = W[(size_t)(k0 + ty + i) * KDIM + n0 + tx];
    __syncthreads();
    #pragma unroll
    for (int i = 0; i < 32; i += 8)
        WT[(size_t)(n0 + ty + i) * KDIM + k0 + tx] = f2bf(tile[tx][ty + i]);
}

// ---------------------------------------------------------------------------
// Staged NT MFMA core: block computes 128x128 f32 tile of A[M,K] @ B[N,K]^T.
// 256 threads / 4 waves, each wave a 64x64 subtile.
// ---------------------------------------------------------------------------
template<int KSTEPS>
__device__ __forceinline__ void mfma_nt_staged(
    const unsigned short* __restrict__ A, const unsigned short* __restrict__ B,
    int lda, int ldb, int bm, int bn,
    unsigned short* AsLDS, unsigned short* BsLDS, f32x4 acc[4][4])
{
    const int t = threadIdx.x;
    const int wv = t >> 6, ln = t & 63;
    const int r = ln & 15, quad = ln >> 4;
    const int wm = (wv >> 1) * 64, wn = (wv & 1) * 64;
    const int srow = wv * 16 + (ln >> 2);
    const int scol = (ln & 3) * 8;

    for (int ks = 0; ks < KSTEPS; ++ks) {
        const int k0 = ks * 32;
        #pragma unroll
        for (int j = 0; j < 2; ++j) {
            gload_lds16(A + (size_t)(bm + j * 64 + srow) * lda + k0 + scol,
                        AsLDS + (size_t)(j * 64 + wv * 16) * 32);
            gload_lds16(B + (size_t)(bn + j * 64 + srow) * ldb + k0 + scol,
                        BsLDS + (size_t)(j * 64 + wv * 16) * 32);
        }
        __syncthreads();
        bf16x8 af[4], bg[4];
        #pragma unroll
        for (int f = 0; f < 4; ++f)
            af[f] = *(const bf16x8*)(AsLDS + (size_t)(wm + f * 16 + r) * 32 + quad * 8);
        #pragma unroll
        for (int f = 0; f < 4; ++f)
            bg[f] = *(const bf16x8*)(BsLDS + (size_t)(wn + f * 16 + r) * 32 + quad * 8);
        #pragma unroll
        for (int i = 0; i < 4; ++i)
            #pragma unroll
            for (int j2 = 0; j2 < 4; ++j2)
                acc[i][j2] = __builtin_amdgcn_mfma_f32_16x16x32_bf16(
                    af[i], bg[j2], acc[i][j2], 0, 0, 0);
        __syncthreads();
    }
}

__device__ __forceinline__ void zero_acc(f32x4 acc[4][4]) {
    #pragma unroll
    for (int i = 0; i < 4; ++i)
        #pragma unroll
        for (int j = 0; j < 4; ++j)
            acc[i][j] = f32x4{0.f, 0.f, 0.f, 0.f};
}

// ---------------------------------------------------------------------------
// Projection: C[M x 1024] bf16 = A[M x 512] @ WT[1024 x 512]^T + bias
// ---------------------------------------------------------------------------
__global__ __launch_bounds__(256) void proj_mfma(
    const unsigned short* __restrict__ A, const unsigned short* __restrict__ WT,
    const float* __restrict__ bias_m, const float* __restrict__ bias_c,
    unsigned short* __restrict__ C)
{
    __shared__ unsigned short As[128 * 32];
    __shared__ unsigned short Bs[128 * 32];
    const int bm = blockIdx.y * 128, bn = blockIdx.x * 128;
    f32x4 acc[4][4]; zero_acc(acc);
    mfma_nt_staged<16>(A, WT, KDIM, KDIM, bm, bn, As, Bs, acc);
    const int wv = threadIdx.x >> 6, ln = threadIdx.x & 63;
    const int r = ln & 15, quad = ln >> 4;
    const int m0 = bm + (wv >> 1) * 64, n0 = bn + (wv & 1) * 64;
    #pragma unroll
    for (int j = 0; j < 4; ++j) {
        const int n = n0 + j * 16 + r;
        const float bv = (n < 512) ? bias_m[n] : bias_c[n - 512];
        #pragma unroll
        for (int i = 0; i < 4; ++i) {
            #pragma unroll
            for (int reg = 0; reg < 4; ++reg) {
                const int m = m0 + i * 16 + quad * 4 + reg;
                C[(size_t)m * 1024 + n] = f2bf(acc[i][j][reg] + bv);
            }
        }
    }
}

// ---------------------------------------------------------------------------
// p_choose: per batch b, p = sigmoid(qm[b] @ km[b]^T / sqrt(512) + r + noise)
// ---------------------------------------------------------------------------
__global__ __launch_bounds__(256) void pchoose_mfma(
    const unsigned short* __restrict__ qp, const unsigned short* __restrict__ kp,
    const float* __restrict__ noise, const float* __restrict__ rp,
    float* __restrict__ p)
{
    __shared__ unsigned short As[128 * 32];
    __shared__ unsigned short Bs[128 * 32];
    const int b = blockIdx.z;
    const unsigned short* A = qp + (size_t)b * QLEN * 1024;
    const unsigned short* B = kp + (size_t)b * KLEN * 1024;
    const int bm = blockIdx.y * 128, bn = blockIdx.x * 128;
    f32x4 acc[4][4]; zero_acc(acc);
    mfma_nt_staged<16>(A, B, 1024, 1024, bm, bn, As, Bs, acc);
    const int wv = threadIdx.x >> 6, ln = threadIdx.x & 63;
    const int r = ln & 15, quad = ln >> 4;
    const int m0 = bm + (wv >> 1) * 64, n0 = bn + (wv & 1) * 64;
    const float rv = rp[0];
    #pragma unroll
    for (int i = 0; i < 4; ++i) {
        #pragma unroll
        for (int reg = 0; reg < 4; ++reg) {
            const int q = m0 + i * 16 + quad * 4 + reg;
            const size_t rowoff = ((size_t)b * QLEN + q) * KLEN;
            #pragma unroll
            for (int j = 0; j < 4; ++j) {
                const int k = n0 + j * 16 + r;
                const float e = acc[i][j][reg] * INV_SCALE + rv + noise[rowoff + k];
                p[rowoff + k] = __builtin_amdgcn_rcpf(1.0f + __expf(-e));
            }
        }
    }
}

// ---------------------------------------------------------------------------
// 64-lane inclusive prefix sum via DPP (≈6 VALU ops)
// ---------------------------------------------------------------------------
__device__ __forceinline__ float wave_incl_scan(float x)
{
#define DPP_ADD(ctrl, rmask, bctrl)                                            \
    { int _t = __builtin_amdgcn_update_dpp(0, __builtin_bit_cast(int, x),      \
                                           ctrl, rmask, 0xf, bctrl);           \
      x += __builtin_bit_cast(float, _t); }
    DPP_ADD(0x111, 0xf, true)   // row_shr:1
    DPP_ADD(0x112, 0xf, true)   // row_shr:2
    DPP_ADD(0x114, 0xf, true)   // row_shr:4
    DPP_ADD(0x118, 0xf, true)   // row_shr:8
    DPP_ADD(0x142, 0xa, false)  // row_bcast:15 -> rows 1,3
    DPP_ADD(0x143, 0xc, false)  // row_bcast:31 -> rows 2,3
#undef DPP_ADD
    return x;
}

// ---------------------------------------------------------------------------
// cumprod_mr: per (b,q) row: cp = exp(excl_cumsum(log(clip(1-p)))); emits
// m = p*cp, r = 1/clip(cp). Fast intrinsics; absorbs all transcendentals.
// NOTE: m/r rows are written in a BANK-SWIZZLED layout (16B group g goes to
// position (g & ~7) | ((g ^ (g>>3)) & 7) within the row). Only the alpha
// scan reads m/r; it applies the matching XOR on its LDS reads. This makes
// the alpha ds_read_b128 pattern bank-balanced (8 words/bank = optimal)
// instead of the 32-way conflict a linear lane-owns-128B layout gives.
// ---------------------------------------------------------------------------
__global__ __launch_bounds__(256) void cumprod_mr(
    const float* __restrict__ p, float* __restrict__ mArr, float* __restrict__ rArr)
{
    const size_t row = blockIdx.x;
    const float* pr = p + row * KLEN;
    float* mr = mArr + row * KLEN;
    float* rr = rArr + row * KLEN;
    const int tid = threadIdx.x;
    const int lane = tid & 63, wid = tid >> 6;
    __shared__ float waveTot[4];

    float4 v0 = *(const float4*)(pr + tid * 8);
    float4 v1 = *(const float4*)(pr + tid * 8 + 4);
    float pv[8] = {v0.x, v0.y, v0.z, v0.w, v1.x, v1.y, v1.z, v1.w};
    float excl[8];
    float run = 0.0f;
    #pragma unroll
    for (int j = 0; j < 8; ++j) {
        float l = __logf(fminf(fmaxf(1.0f - pv[j], EPSV), 1.0f));
        excl[j] = run;
        run += l;
    }
    float s = wave_incl_scan(run);
    if (lane == 63) waveTot[wid] = s;
    __syncthreads();
    float wex = 0.0f;
    for (int w = 0; w < wid; ++w) wex += waveTot[w];
    const float texcl = wex + s - run;

    float mv[8], rv[8];
    #pragma unroll
    for (int j = 0; j < 8; ++j) {
        const float cpv = __expf(texcl + excl[j]);
        mv[j] = pv[j] * cpv;
        rv[j] = __builtin_amdgcn_rcpf(fminf(fmaxf(cpv, EPSV), 1.0f));
    }
    // swizzled 16B-group positions (involution within each 128B block)
    const int g0 = tid * 2, g1 = g0 + 1;
    const int G0 = (g0 & ~7) | ((g0 ^ (g0 >> 3)) & 7);
    const int G1 = (g1 & ~7) | ((g1 ^ (g1 >> 3)) & 7);
    *(float4*)(mr + G0 * 4) = *(float4*)&mv[0];
    *(float4*)(mr + G1 * 4) = *(float4*)&mv[4];
    *(float4*)(rr + G0 * 4) = *(float4*)&rv[0];
    *(float4*)(rr + G1 * 4) = *(float4*)&rv[4];
}

// ---------------------------------------------------------------------------
// alpha_echunk: FUSED kernel.
//  Blocks 0..7: single-wave alpha recurrence, LDS-ring streamed.
//    R1 post-mortem: register double-buffering needed ~190 VGPRs; compiler
//    capped at 128 and spilled to scratch (794 us). Fix: prefetch m/r rows
//    3 steps ahead via global_load_lds into a 3-slot x 16KB LDS ring (zero
//    VGPR cost), consume with counted s_waitcnt vmcnt(N) (never 0). Live
//    regs: aw(32)+rc(32)+mc(32)+temps ~ 115 -> no spills. ds_reads use the
//    XOR-swizzled row layout written by cumprod_mr (bank-balanced b128).
//    vmcnt accounting (retire-in-order): per step = 8 stores + 16 loads;
//    steady wait = 2*16+2*8 = 48; prologue peels 32/40, tail peels 48/32/16.
//  Blocks 8..1031: e_chunk MFMA tiles (unchanged; fill the idle CUs).
// ---------------------------------------------------------------------------
__global__ __launch_bounds__(512, 1) void alpha_echunk(
    const float* __restrict__ mArr, const float* __restrict__ rArr,
    float* __restrict__ alpha,
    const unsigned short* __restrict__ qp, const unsigned short* __restrict__ kp,
    float* __restrict__ out)
{
    __shared__ __align__(16) char smem[49152];
    const int bid = blockIdx.x;
    const int tid = threadIdx.x;

    if (bid < BATCH) {
        // ---------------- single-wave alpha scan, LDS ring ----------------
        if (tid >= 64) return;           // waves 1..7 exit (no barrier here)
        const int l = tid;               // lane 0..63
        const int sw = l & 7;            // read-side XOR swizzle key
        const size_t rowbase = (size_t)bid * QLEN * KLEN;
        const float* mB = mArr + rowbase;    // swizzled rows
        const float* rB = rArr + rowbase;
        float* ab = alpha + rowbase + (size_t)l * 32;

        char* p0 = smem;                 // slot for current step
        char* p1 = smem + 16384;
        char* p2 = smem + 32768;

        // prologue: stage rows 0,1,2 (16 gload_lds each, m then r)
        #pragma unroll
        for (int st = 0; st < 3; ++st) {
            #pragma unroll
            for (int t = 0; t < 8; ++t)
                gload_lds16(mB + (size_t)st * KLEN + t * 256 + l * 4,
                            smem + st * 16384 + t * 1024);
            #pragma unroll
            for (int t = 0; t < 8; ++t)
                gload_lds16(rB + (size_t)st * KLEN + t * 256 + l * 4,
                            smem + st * 16384 + 8192 + t * 1024);
        }

        float4 aw[8];
        #pragma unroll
        for (int j = 0; j < 8; ++j) aw[j] = float4{0.f, 0.f, 0.f, 0.f};
        if (l == 0) aw[0].x = 1.0f;      // one-hot at k=0

// in-lane group chain: 8 elems (2 float4s), prefix written in place into aw
#define GRP(c, J0, J1)                                                         \
        c = fmaf(aw[J0].x, rc[J0].x, c); aw[J0].x = c;                         \
        c = fmaf(aw[J0].y, rc[J0].y, c); aw[J0].y = c;                         \
        c = fmaf(aw[J0].z, rc[J0].z, c); aw[J0].z = c;                         \
        c = fmaf(aw[J0].w, rc[J0].w, c); aw[J0].w = c;                         \
        c = fmaf(aw[J1].x, rc[J1].x, c); aw[J1].x = c;                         \
        c = fmaf(aw[J1].y, rc[J1].y, c); aw[J1].y = c;                         \
        c = fmaf(aw[J1].z, rc[J1].z, c); aw[J1].z = c;                         \
        c = fmaf(aw[J1].w, rc[J1].w, c); aw[J1].w = c;

#define EPI(J0, J1, Bg)                                                        \
        aw[J0].x = mc[J0].x * (Bg + aw[J0].x);                                 \
        aw[J0].y = mc[J0].y * (Bg + aw[J0].y);                                 \
        aw[J0].z = mc[J0].z * (Bg + aw[J0].z);                                 \
        aw[J0].w = mc[J0].w * (Bg + aw[J0].w);                                 \
        aw[J1].x = mc[J1].x * (Bg + aw[J1].x);                                 \
        aw[J1].y = mc[J1].y * (Bg + aw[J1].y);                                 \
        aw[J1].z = mc[J1].z * (Bg + aw[J1].z);                                 \
        aw[J1].w = mc[J1].w * (Bg + aw[J1].w);

#define ASTEP(IEXPR, WN, PREF)                                                 \
    {                                                                          \
        const int i_ = (IEXPR);                                                \
        asm volatile("s_waitcnt vmcnt(" #WN ")" ::: "memory");                 \
        __builtin_amdgcn_sched_barrier(0);                                     \
        const float* mS = (const float*)p0;                                    \
        const float* rS = (const float*)(p0 + 8192);                           \
        const int bi = l * 32;                                                 \
        float4 rc[8], mc[8];                                                   \
        rc[0] = *(const float4*)(rS + bi + ((0 ^ sw) << 2));                   \
        rc[1] = *(const float4*)(rS + bi + ((1 ^ sw) << 2));                   \
        rc[2] = *(const float4*)(rS + bi + ((2 ^ sw) << 2));                   \
        rc[3] = *(const float4*)(rS + bi + ((3 ^ sw) << 2));                   \
        rc[4] = *(const float4*)(rS + bi + ((4 ^ sw) << 2));                   \
        rc[5] = *(const float4*)(rS + bi + ((5 ^ sw) << 2));                   \
        rc[6] = *(const float4*)(rS + bi + ((6 ^ sw) << 2));                   \
        rc[7] = *(const float4*)(rS + bi + ((7 ^ sw) << 2));                   \
        mc[0] = *(const float4*)(mS + bi + ((0 ^ sw) << 2));                   \
        mc[1] = *(const float4*)(mS + bi + ((1 ^ sw) << 2));                   \
        mc[2] = *(const float4*)(mS + bi + ((2 ^ sw) << 2));                   \
        mc[3] = *(const float4*)(mS + bi + ((3 ^ sw) << 2));                   \
        mc[4] = *(const float4*)(mS + bi + ((4 ^ sw) << 2));                   \
        mc[5] = *(const float4*)(mS + bi + ((5 ^ sw) << 2));                   \
        mc[6] = *(const float4*)(mS + bi + ((6 ^ sw) << 2));                   \
        mc[7] = *(const float4*)(mS + bi + ((7 ^ sw) << 2));                   \
        float t0 = 0.f, t1 = 0.f, t2 = 0.f, t3 = 0.f;                          \
        GRP(t0, 0, 1)                                                          \
        GRP(t1, 2, 3)                                                          \
        GRP(t2, 4, 5)                                                          \
        GRP(t3, 6, 7)                                                          \
        const float o1 = t0, o2 = o1 + t1, o3 = o2 + t2;                       \
        float run = o3 + t3;                                                   \
        const float s_ = wave_incl_scan(run);                                  \
        const float base = s_ - run;                                           \
        const float B0 = base, B1 = base + o1, B2 = base + o2, B3 = base + o3; \
        EPI(0, 1, B0)                                                          \
        EPI(2, 3, B1)                                                          \
        EPI(4, 5, B2)                                                          \
        EPI(6, 7, B3)                                                          \
        float* ao = ab + (size_t)i_ * KLEN;                                    \
        *(float4*)(ao)      = aw[0];                                           \
        *(float4*)(ao + 4)  = aw[1];                                           \
        *(float4*)(ao + 8)  = aw[2];                                           \
        *(float4*)(ao + 12) = aw[3];                                           \
        *(float4*)(ao + 16) = aw[4];                                           \
        *(float4*)(ao + 20) = aw[5];                                           \
        *(float4*)(ao + 24) = aw[6];                                           \
        *(float4*)(ao + 28) = aw[7];                                           \
        if (PREF) {                                                            \
            asm volatile("s_waitcnt lgkmcnt(0)" ::: "memory");                 \
            __builtin_amdgcn_sched_barrier(0);                                 \
            const float* gm = mB + (size_t)(i_ + 3) * KLEN + l * 4;            \
            const float* gr = rB + (size_t)(i_ + 3) * KLEN + l * 4;            \
            gload_lds16(gm,        p0);                                        \
            gload_lds16(gm + 256,  p0 + 1024);                                 \
            gload_lds16(gm + 512,  p0 + 2048);                                 \
            gload_lds16(gm + 768,  p0 + 3072);                                 \
            gload_lds16(gm + 1024, p0 + 4096);                                 \
            gload_lds16(gm + 1280, p0 + 5120);                                 \
            gload_lds16(gm + 1536, p0 + 6144);                                 \
            gload_lds16(gm + 1792, p0 + 7168);                                 \
            gload_lds16(gr,        p0 + 8192);                                 \
            gload_lds16(gr + 256,  p0 + 9216);                                 \
            gload_lds16(gr + 512,  p0 + 10240);                                \
            gload_lds16(gr + 768,  p0 + 11264);                                \
            gload_lds16(gr + 1024, p0 + 12288);                                \
            gload_lds16(gr + 1280, p0 + 13312);                                \
            gload_lds16(gr + 1536, p0 + 14336);                                \
            gload_lds16(gr + 1792, p0 + 15360);                                \
        }                                                                      \
        { char* tp_ = p0; p0 = p1; p1 = p2; p2 = tp_; }                        \
    }

        ASTEP(0, 32, 1)
        ASTEP(1, 40, 1)
        for (int io = 2; io <= 252; ++io) {
            ASTEP(io, 48, 1)
        }
        ASTEP(253, 48, 0)
        ASTEP(254, 32, 0)
        ASTEP(255, 16, 0)
#undef ASTEP
#undef EPI
#undef GRP
        return;
    }

    // ---------------- echunk tile ----------------
    const int v = bid - BATCH;           // 0..1023
    const int z = v >> 5;                // 0..31 = b*4+h
    const int by = (v >> 4) & 1;
    const int bx = v & 15;
    const int b = z >> 2, h = z & 3;
    const bool worker = tid < 256;
    unsigned short* As = (unsigned short*)smem;            // 8 KB
    unsigned short* Bs = (unsigned short*)(smem + 8192);   // 8 KB
    const unsigned short* A = qp + (size_t)b * QLEN * 1024 + 512 + h * DKH;
    const unsigned short* B = kp + (size_t)b * KLEN * 1024 + 512 + h * DKH;
    const int bm = by * 128, bn = bx * 128;

    const int wv = tid >> 6, ln = tid & 63;
    const int r = ln & 15, quad = ln >> 4;
    const int wm = (wv >> 1) * 64, wn = (wv & 1) * 64;
    const int srow = (wv & 3) * 16 + (ln >> 2);
    const int scol = (ln & 3) * 8;

    f32x4 acc[4][4]; zero_acc(acc);
    for (int ks = 0; ks < 4; ++ks) {
        const int k0 = ks * 32;
        if (worker) {
            #pragma unroll
            for (int j = 0; j < 2; ++j) {
                gload_lds16(A + (size_t)(bm + j * 64 + srow) * 1024 + k0 + scol,
                            As + (size_t)(j * 64 + wv * 16) * 32);
                gload_lds16(B + (size_t)(bn + j * 64 + srow) * 1024 + k0 + scol,
                            Bs + (size_t)(j * 64 + wv * 16) * 32);
            }
        }
        __syncthreads();
        if (worker) {
            bf16x8 af[4], bg[4];
            #pragma unroll
            for (int f = 0; f < 4; ++f)
                af[f] = *(const bf16x8*)(As + (size_t)(wm + f * 16 + r) * 32 + quad * 8);
            #pragma unroll
            for (int f = 0; f < 4; ++f)
                bg[f] = *(const bf16x8*)(Bs + (size_t)(wn + f * 16 + r) * 32 + quad * 8);
            #pragma unroll
            for (int i = 0; i < 4; ++i)
                #pragma unroll
                for (int j2 = 0; j2 < 4; ++j2)
                    acc[i][j2] = __builtin_amdgcn_mfma_f32_16x16x32_bf16(
                        af[i], bg[j2], acc[i][j2], 0, 0, 0);
        }
        __syncthreads();
    }
    if (worker) {
        const int m0 = bm + (wv >> 1) * 64, n0 = bn + (wv & 1) * 64;
        #pragma unroll
        for (int i = 0; i < 4; ++i) {
            #pragma unroll
            for (int reg = 0; reg < 4; ++reg) {
                const int q = m0 + i * 16 + quad * 4 + reg;
                const size_t rowoff = ((size_t)z * QLEN + q) * KLEN;
                #pragma unroll
                for (int j = 0; j < 4; ++j) {
                    const int k = n0 + j * 16 + r;
                    out[rowoff + k] = acc[i][j][reg] * INV_SCALE;
                }
            }
        }
    }
}

// ---------------------------------------------------------------------------
// beta: per (b,h,q) row of 2048 (e_chunk in d_out, overwritten)
// ---------------------------------------------------------------------------
__global__ __launch_bounds__(256) void beta_kernel(
    float* __restrict__ eo, const float* __restrict__ alpha)
{
    __shared__ float sse[KLEN + 3];
    __shared__ float su[KLEN + 3];
    __shared__ float wmax[4];

    const int tid = threadIdx.x;
    const int lane = tid & 63, wid = tid >> 6;
    const int row = blockIdx.x;                 // [B*H*Q]
    const int q = row & (QLEN - 1);
    const int b = row >> 10;
    float* erow = eo + (size_t)row * KLEN;
    const float* arow = alpha + ((size_t)b * QLEN + q) * KLEN;

    if (tid < 3) { sse[tid] = 0.0f; su[KLEN + tid] = 0.0f; }

    float ev[8];
    float lm = -INFINITY;
    #pragma unroll
    for (int j = 0; j < 8; ++j) {
        const int k = tid + 256 * j;
        ev[j] = erow[k];
        lm = fmaxf(lm, ev[j]);
    }
    #pragma unroll
    for (int off = 32; off > 0; off >>= 1) lm = fmaxf(lm, __shfl_xor(lm, off));
    if (lane == 0) wmax[wid] = lm;
    __syncthreads();
    const float mx = fmaxf(fmaxf(wmax[0], wmax[1]), fmaxf(wmax[2], wmax[3]));

    #pragma unroll
    for (int j = 0; j < 8; ++j) {
        const int k = tid + 256 * j;
        sse[k + 3] = fmaxf(__expf(ev[j] - mx), 1e-5f);
    }
    __syncthreads();

    #pragma unroll
    for (int j = 0; j < 8; ++j) {
        const int k = tid + 256 * j;
        const float denom = sse[k + 3] + sse[k + 2] + sse[k + 1] + sse[k];
        su[k] = arow[k] * __builtin_amdgcn_rcpf(denom);
    }
    __syncthreads();

    #pragma unroll
    for (int j = 0; j < 8; ++j) {
        const int k = tid + 256 * j;
        erow[k] = sse[k + 3] * (su[k] + su[k + 1] + su[k + 2] + su[k + 3]);
    }
}

// ---------------------------------------------------------------------------
extern "C" void kernel_launch(void* const* d_in, const int* in_sizes, int n_in,
                              void* d_out, int out_size, void* d_ws, size_t ws_size,
                              hipStream_t stream)
{
    (void)in_sizes; (void)n_in; (void)out_size; (void)ws_size;
    const float* key_enc = (const float*)d_in[0];   // [8,2048,512]
    const float* query   = (const float*)d_in[1];   // [8,256,512]
    const float* noise   = (const float*)d_in[2];   // [8,256,2048]
    const float* Wk_m    = (const float*)d_in[3];
    const float* bk_m    = (const float*)d_in[4];
    const float* Wq_m    = (const float*)d_in[5];
    const float* bq_m    = (const float*)d_in[6];
    const float* rp      = (const float*)d_in[7];
    const float* Wk_c    = (const float*)d_in[8];
    const float* bk_c    = (const float*)d_in[9];
    const float* Wq_c    = (const float*)d_in[10];
    const float* bq_c    = (const float*)d_in[11];
    float* out = (float*)d_out;                     // [8,4,256,2048]

    // workspace layout (bytes)
    char* w = (char*)d_ws;
    unsigned short* kx    = (unsigned short*)w; w += (size_t)BATCH * KLEN * KDIM * 2;   // 16.8 MB
    unsigned short* qx    = (unsigned short*)w; w += (size_t)BATCH * QLEN * KDIM * 2;   //  2.1 MB
    unsigned short* WTk   = (unsigned short*)w; w += (size_t)1024 * KDIM * 2;           //  1.0 MB
    unsigned short* WTq   = (unsigned short*)w; w += (size_t)1024 * KDIM * 2;           //  1.0 MB
    unsigned short* kproj = (unsigned short*)w; w += (size_t)BATCH * KLEN * 1024 * 2;   // 33.6 MB
    unsigned short* qproj = (unsigned short*)w; w += (size_t)BATCH * QLEN * 1024 * 2;   //  4.2 MB
    float* p_alpha = (float*)w; w += (size_t)BATCH * QLEN * KLEN * 4;                   // 16.8 MB
    float* mArr    = (float*)w; w += (size_t)BATCH * QLEN * KLEN * 4;                   // 16.8 MB
    float* rArr    = (float*)w;                                                         // 16.8 MB

    // 1) casts
    hipLaunchKernelGGL(cast_bf16, dim3(BATCH * KLEN * KDIM / 4 / 256), dim3(256), 0, stream,
                       key_enc, kx, BATCH * KLEN * KDIM / 4);
    hipLaunchKernelGGL(cast_bf16, dim3(BATCH * QLEN * KDIM / 4 / 256), dim3(256), 0, stream,
                       query, qx, BATCH * QLEN * KDIM / 4);
    hipLaunchKernelGGL(transpose_cast, dim3(16, 16), dim3(32, 8), 0, stream, Wk_m, WTk);
    hipLaunchKernelGGL(transpose_cast, dim3(16, 16), dim3(32, 8), 0, stream, Wk_c, WTk + (size_t)512 * KDIM);
    hipLaunchKernelGGL(transpose_cast, dim3(16, 16), dim3(32, 8), 0, stream, Wq_m, WTq);
    hipLaunchKernelGGL(transpose_cast, dim3(16, 16), dim3(32, 8), 0, stream, Wq_c, WTq + (size_t)512 * KDIM);

    // 2) projections (staged bf16 MFMA, fused bias, bf16 out)
    hipLaunchKernelGGL(proj_mfma, dim3(8, BATCH * KLEN / 128), dim3(256), 0, stream,
                       kx, WTk, bk_m, bk_c, kproj);
    hipLaunchKernelGGL(proj_mfma, dim3(8, BATCH * QLEN / 128), dim3(256), 0, stream,
                       qx, WTq, bq_m, bq_c, qproj);

    // 3) p_choose (staged bf16 MFMA + fast sigmoid epilogue)
    hipLaunchKernelGGL(pchoose_mfma, dim3(KLEN / 128, QLEN / 128, BATCH), dim3(256), 0, stream,
                       qproj, kproj, noise, rp, p_alpha);

    // 4) cumprod -> (m, r) in swizzled row layout (parallel, absorbs transcendentals)
    hipLaunchKernelGGL(cumprod_mr, dim3(BATCH * QLEN), dim3(256), 0, stream,
                       p_alpha, mArr, rArr);

    // 5) FUSED: alpha recurrence (blocks 0..7, single-wave LDS ring) +
    //           e_chunk (blocks 8..1031)
    hipLaunchKernelGGL(alpha_echunk, dim3(BATCH + KLEN / 128 * QLEN / 128 * BATCH * NHEADS),
                       dim3(512), 0, stream,
                       mArr, rArr, p_alpha, qproj, kproj, out);

    // 6) beta (overwrites e_chunk rows in d_out)
    hipLaunchKernelGGL(beta_kernel, dim3(BATCH * NHEADS * QLEN), dim3(256), 0, stream,
                       out, p_alpha);
}

// Round 3
// 307.565 us; speedup vs baseline: 3.2778x; 1.5292x over previous
//
#include <hip/hip_runtime.h>
#include <math.h>

// Problem constants
#define BATCH   8
#define QLEN    256
#define KLEN    2048
#define KDIM    512
#define ADIMC   512
#define NHEADS  4
#define DKH     128
#define CHUNKW  4

static constexpr float INV_SCALE = 0.04419417382415922f; // 1/sqrt(512)
static constexpr float EPSV = 1e-6f;

typedef __attribute__((ext_vector_type(8))) short bf16x8;
typedef __attribute__((ext_vector_type(4))) float f32x4;

__device__ __forceinline__ unsigned short f2bf(float f) {
    unsigned u = __builtin_bit_cast(unsigned, f);
    u += 0x7fffu + ((u >> 16) & 1u);   // round-to-nearest-even
    return (unsigned short)(u >> 16);
}

// Barrier waiting only on LDS ops (lgkmcnt); global loads/stores stay in flight.
__device__ __forceinline__ void lds_barrier() {
    __asm__ volatile("s_waitcnt lgkmcnt(0)\n\ts_barrier" ::: "memory");
}

// Async global->LDS, 16 B per lane (wave-uniform base + lane*16 rule).
__device__ __forceinline__ void gload_lds16(const void* g, void* l) {
    __builtin_amdgcn_global_load_lds(
        (const __attribute__((address_space(1))) void*)g,
        (__attribute__((address_space(3))) void*)l, 16, 0, 0);
}

// ---------------------------------------------------------------------------
// Elementwise f32 -> bf16 cast (4 elems/thread)
// ---------------------------------------------------------------------------
__global__ __launch_bounds__(256) void cast_bf16(
    const float* __restrict__ x, unsigned short* __restrict__ y, int n4)
{
    int i = blockIdx.x * 256 + threadIdx.x;
    if (i < n4) {
        float4 v = ((const float4*)x)[i];
        ushort4 o;
        o.x = f2bf(v.x); o.y = f2bf(v.y); o.z = f2bf(v.z); o.w = f2bf(v.w);
        ((ushort4*)y)[i] = o;
    }
}

// ---------------------------------------------------------------------------
// Transpose-cast: W [512 x 512] (k-major rows) -> WT [512 x 512] bf16, WT[n][k]
// ---------------------------------------------------------------------------
__global__ __launch_bounds__(256) void transpose_cast(
    const float* __restrict__ W, unsigned short* __restrict__ WT)
{
    __shared__ float tile[32][33];
    const int tx = threadIdx.x;          // 0..31
    const int ty = threadIdx.y;          // 0..7
    const int k0 = blockIdx.y * 32, n0 = blockIdx.x * 32;
    #pragma unroll
    for (int i = 0; i < 32; i += 8)
        tile[ty + i][tx] = W[(size_t)(k0 + ty + i) * KDIM + n0 + tx];
    __syncthreads();
    #pragma unroll
    for (int i = 0; i < 32; i += 8)
        WT[(size_t)(n0 + ty + i) * KDIM + k0 + tx] = f2bf(tile[tx][ty + i]);
}

// ---------------------------------------------------------------------------
// Staged NT MFMA core: block computes 128x128 f32 tile of A[M,K] @ B[N,K]^T.
// 256 threads / 4 waves, each wave a 64x64 subtile.
// ---------------------------------------------------------------------------
template<int KSTEPS>
__device__ __forceinline__ void mfma_nt_staged(
    const unsigned short* __restrict__ A, const unsigned short* __restrict__ B,
    int lda, int ldb, int bm, int bn,
    unsigned short* AsLDS, unsigned short* BsLDS, f32x4 acc[4][4])
{
    const int t = threadIdx.x;
    const int wv = t >> 6, ln = t & 63;
    const int r = ln & 15, quad = ln >> 4;
    const int wm = (wv >> 1) * 64, wn = (wv & 1) * 64;
    const int srow = wv * 16 + (ln >> 2);
    const int scol = (ln & 3) * 8;

    for (int ks = 0; ks < KSTEPS; ++ks) {
        const int k0 = ks * 32;
        #pragma unroll
        for (int j = 0; j < 2; ++j) {
            gload_lds16(A + (size_t)(bm + j * 64 + srow) * lda + k0 + scol,
                        AsLDS + (size_t)(j * 64 + wv * 16) * 32);
            gload_lds16(B + (size_t)(bn + j * 64 + srow) * ldb + k0 + scol,
                        BsLDS + (size_t)(j * 64 + wv * 16) * 32);
        }
        __syncthreads();
        bf16x8 af[4], bg[4];
        #pragma unroll
        for (int f = 0; f < 4; ++f)
            af[f] = *(const bf16x8*)(AsLDS + (size_t)(wm + f * 16 + r) * 32 + quad * 8);
        #pragma unroll
        for (int f = 0; f < 4; ++f)
            bg[f] = *(const bf16x8*)(BsLDS + (size_t)(wn + f * 16 + r) * 32 + quad * 8);
        #pragma unroll
        for (int i = 0; i < 4; ++i)
            #pragma unroll
            for (int j2 = 0; j2 < 4; ++j2)
                acc[i][j2] = __builtin_amdgcn_mfma_f32_16x16x32_bf16(
                    af[i], bg[j2], acc[i][j2], 0, 0, 0);
        __syncthreads();
    }
}

__device__ __forceinline__ void zero_acc(f32x4 acc[4][4]) {
    #pragma unroll
    for (int i = 0; i < 4; ++i)
        #pragma unroll
        for (int j = 0; j < 4; ++j)
            acc[i][j] = f32x4{0.f, 0.f, 0.f, 0.f};
}

// ---------------------------------------------------------------------------
// Projection: C[M x 1024] bf16 = A[M x 512] @ WT[1024 x 512]^T + bias
// ---------------------------------------------------------------------------
__global__ __launch_bounds__(256) void proj_mfma(
    const unsigned short* __restrict__ A, const unsigned short* __restrict__ WT,
    const float* __restrict__ bias_m, const float* __restrict__ bias_c,
    unsigned short* __restrict__ C)
{
    __shared__ unsigned short As[128 * 32];
    __shared__ unsigned short Bs[128 * 32];
    const int bm = blockIdx.y * 128, bn = blockIdx.x * 128;
    f32x4 acc[4][4]; zero_acc(acc);
    mfma_nt_staged<16>(A, WT, KDIM, KDIM, bm, bn, As, Bs, acc);
    const int wv = threadIdx.x >> 6, ln = threadIdx.x & 63;
    const int r = ln & 15, quad = ln >> 4;
    const int m0 = bm + (wv >> 1) * 64, n0 = bn + (wv & 1) * 64;
    #pragma unroll
    for (int j = 0; j < 4; ++j) {
        const int n = n0 + j * 16 + r;
        const float bv = (n < 512) ? bias_m[n] : bias_c[n - 512];
        #pragma unroll
        for (int i = 0; i < 4; ++i) {
            #pragma unroll
            for (int reg = 0; reg < 4; ++reg) {
                const int m = m0 + i * 16 + quad * 4 + reg;
                C[(size_t)m * 1024 + n] = f2bf(acc[i][j][reg] + bv);
            }
        }
    }
}

// ---------------------------------------------------------------------------
// p_choose: per batch b, p = sigmoid(qm[b] @ km[b]^T / sqrt(512) + r + noise)
// ---------------------------------------------------------------------------
__global__ __launch_bounds__(256) void pchoose_mfma(
    const unsigned short* __restrict__ qp, const unsigned short* __restrict__ kp,
    const float* __restrict__ noise, const float* __restrict__ rp,
    float* __restrict__ p)
{
    __shared__ unsigned short As[128 * 32];
    __shared__ unsigned short Bs[128 * 32];
    const int b = blockIdx.z;
    const unsigned short* A = qp + (size_t)b * QLEN * 1024;
    const unsigned short* B = kp + (size_t)b * KLEN * 1024;
    const int bm = blockIdx.y * 128, bn = blockIdx.x * 128;
    f32x4 acc[4][4]; zero_acc(acc);
    mfma_nt_staged<16>(A, B, 1024, 1024, bm, bn, As, Bs, acc);
    const int wv = threadIdx.x >> 6, ln = threadIdx.x & 63;
    const int r = ln & 15, quad = ln >> 4;
    const int m0 = bm + (wv >> 1) * 64, n0 = bn + (wv & 1) * 64;
    const float rv = rp[0];
    #pragma unroll
    for (int i = 0; i < 4; ++i) {
        #pragma unroll
        for (int reg = 0; reg < 4; ++reg) {
            const int q = m0 + i * 16 + quad * 4 + reg;
            const size_t rowoff = ((size_t)b * QLEN + q) * KLEN;
            #pragma unroll
            for (int j = 0; j < 4; ++j) {
                const int k = n0 + j * 16 + r;
                const float e = acc[i][j][reg] * INV_SCALE + rv + noise[rowoff + k];
                p[rowoff + k] = __builtin_amdgcn_rcpf(1.0f + __expf(-e));
            }
        }
    }
}

// ---------------------------------------------------------------------------
// 64-lane inclusive prefix sum via DPP (≈6 VALU ops)
// ---------------------------------------------------------------------------
__device__ __forceinline__ float wave_incl_scan(float x)
{
#define DPP_ADD(ctrl, rmask, bctrl)                                            \
    { int _t = __builtin_amdgcn_update_dpp(0, __builtin_bit_cast(int, x),      \
                                           ctrl, rmask, 0xf, bctrl);           \
      x += __builtin_bit_cast(float, _t); }
    DPP_ADD(0x111, 0xf, true)   // row_shr:1
    DPP_ADD(0x112, 0xf, true)   // row_shr:2
    DPP_ADD(0x114, 0xf, true)   // row_shr:4
    DPP_ADD(0x118, 0xf, true)   // row_shr:8
    DPP_ADD(0x142, 0xa, false)  // row_bcast:15 -> rows 1,3
    DPP_ADD(0x143, 0xc, false)  // row_bcast:31 -> rows 2,3
#undef DPP_ADD
    return x;
}

// ---------------------------------------------------------------------------
// cumprod_mr: per (b,q) row: cp = exp(excl_cumsum(log(clip(1-p)))); emits
// m = p*cp, r = 1/clip(cp). Fast intrinsics; absorbs all transcendentals.
// ---------------------------------------------------------------------------
__global__ __launch_bounds__(256) void cumprod_mr(
    const float* __restrict__ p, float* __restrict__ mArr, float* __restrict__ rArr)
{
    const size_t row = blockIdx.x;
    const float* pr = p + row * KLEN;
    float* mr = mArr + row * KLEN;
    float* rr = rArr + row * KLEN;
    const int tid = threadIdx.x;
    const int lane = tid & 63, wid = tid >> 6;
    __shared__ float waveTot[4];

    float4 v0 = *(const float4*)(pr + tid * 8);
    float4 v1 = *(const float4*)(pr + tid * 8 + 4);
    float pv[8] = {v0.x, v0.y, v0.z, v0.w, v1.x, v1.y, v1.z, v1.w};
    float excl[8];
    float run = 0.0f;
    #pragma unroll
    for (int j = 0; j < 8; ++j) {
        float l = __logf(fminf(fmaxf(1.0f - pv[j], EPSV), 1.0f));
        excl[j] = run;
        run += l;
    }
    float s = wave_incl_scan(run);
    if (lane == 63) waveTot[wid] = s;
    __syncthreads();
    float wex = 0.0f;
    for (int w = 0; w < wid; ++w) wex += waveTot[w];
    const float texcl = wex + s - run;

    float mv[8], rv[8];
    #pragma unroll
    for (int j = 0; j < 8; ++j) {
        const float cpv = __expf(texcl + excl[j]);
        mv[j] = pv[j] * cpv;
        rv[j] = __builtin_amdgcn_rcpf(fminf(fmaxf(cpv, EPSV), 1.0f));
    }
    *(float4*)(mr + tid * 8)     = *(float4*)&mv[0];
    *(float4*)(mr + tid * 8 + 4) = *(float4*)&mv[4];
    *(float4*)(rr + tid * 8)     = *(float4*)&rv[0];
    *(float4*)(rr + tid * 8 + 4) = *(float4*)&rv[4];
}

// ---------------------------------------------------------------------------
// alpha_echunk: FUSED kernel. Blocks 0..7: the proven 8-wave alpha recurrence
// (R0 structure, 89 us measured; coalesced 4-elems/lane layout). Blocks
// 8..1031: e_chunk MFMA tiles.
//
// R3 changes (perf-only, no correctness surface):
//  * smem padded to 96 KB -> exactly 1 block/CU. R0's 16 KB let ~8 echunk
//    blocks co-reside on each alpha CU; their global_load_lds staging, MFMA
//    issue and syncthreads stole the LDS pipe + issue slots from alpha's
//    256 serial barrier-steps (theory for R0's 835 cyc/step vs ~350 modeled).
//    Now alpha waves own their CU outright. Echunk (1024 blocks x ~2 us,
//    1/CU over ~248 CUs) still finishes well under alpha's shadow.
//  * s_setprio(1) on alpha waves (T5) in case any co-residency remains.
// R1/R2 lesson (single-wave alpha): issue-serialization (~8x) + memory-
// concurrency exposure beat the barrier saving — 8-wave is the right shape.
// ---------------------------------------------------------------------------
__global__ __launch_bounds__(512, 1) void alpha_echunk(
    const float* __restrict__ mArr, const float* __restrict__ rArr,
    float* __restrict__ alpha,
    const unsigned short* __restrict__ qp, const unsigned short* __restrict__ kp,
    float* __restrict__ out)
{
    __shared__ __align__(16) char smem[98304];   // 96 KB -> 1 block/CU
    const int bid = blockIdx.x;
    const int tid = threadIdx.x;

    if (bid < BATCH) {
        // ---------------- alpha scan (R0 structure) ----------------
        __builtin_amdgcn_s_setprio(1);
        float (*wt)[8] = (float (*)[8])smem;   // [2][8]
        const int lane = tid & 63, wid = tid >> 6;
        const float* mrow = mArr + (size_t)bid * QLEN * KLEN + tid * 4;
        const float* rrow = rArr + (size_t)bid * QLEN * KLEN + tid * 4;
        float* arow = alpha + (size_t)bid * QLEN * KLEN + tid * 4;

        float aw0 = 0.f, aw1 = 0.f, aw2 = 0.f, aw3 = 0.f;
        if (tid == 0) aw0 = 1.0f;   // aw_prev one-hot at k=0

        float4 mA = *(const float4*)(mrow);
        float4 rA = *(const float4*)(rrow);
        float4 mB = *(const float4*)(mrow + KLEN);
        float4 rB = *(const float4*)(rrow + KLEN);

#define ASTEP(I, MREG, RREG)                                                   \
    {                                                                          \
        const int i_ = (I);                                                    \
        float4 mc = MREG, rc = RREG;                                           \
        const int rn_ = (i_ + 2 < QLEN) ? (i_ + 2) : (QLEN - 1);               \
        MREG = *(const float4*)(mrow + (size_t)rn_ * KLEN);                    \
        RREG = *(const float4*)(rrow + (size_t)rn_ * KLEN);                    \
        float run = 0.0f, i0, i1, i2, i3;                                      \
        run = fmaf(aw0, rc.x, run); i0 = run;                                  \
        run = fmaf(aw1, rc.y, run); i1 = run;                                  \
        run = fmaf(aw2, rc.z, run); i2 = run;                                  \
        run = fmaf(aw3, rc.w, run); i3 = run;                                  \
        float tot = wave_incl_scan(run);                                       \
        if (lane == 63) wt[i_ & 1][wid] = tot;                                 \
        lds_barrier();                                                         \
        float base = tot - run;                                                \
        float4 w0 = *(const float4*)&wt[i_ & 1][0];                            \
        float4 w1 = *(const float4*)&wt[i_ & 1][4];                            \
        if (wid > 0) base += w0.x;                                             \
        if (wid > 1) base += w0.y;                                             \
        if (wid > 2) base += w0.z;                                             \
        if (wid > 3) base += w0.w;                                             \
        if (wid > 4) base += w1.x;                                             \
        if (wid > 5) base += w1.y;                                             \
        if (wid > 6) base += w1.z;                                             \
        aw0 = mc.x * (base + i0);                                              \
        aw1 = mc.y * (base + i1);                                              \
        aw2 = mc.z * (base + i2);                                              \
        aw3 = mc.w * (base + i3);                                              \
        float4 ov; ov.x = aw0; ov.y = aw1; ov.z = aw2; ov.w = aw3;             \
        *(float4*)(arow + (size_t)i_ * KLEN) = ov;                             \
    }

        for (int io = 0; io < QLEN; io += 2) {
            ASTEP(io + 0, mA, rA)
            ASTEP(io + 1, mB, rB)
        }
#undef ASTEP
        __builtin_amdgcn_s_setprio(0);
        return;
    }

    // ---------------- echunk tile ----------------
    const int v = bid - BATCH;           // 0..1023
    const int z = v >> 5;                // 0..31 = b*4+h
    const int by = (v >> 4) & 1;
    const int bx = v & 15;
    const int b = z >> 2, h = z & 3;
    const bool worker = tid < 256;
    unsigned short* As = (unsigned short*)smem;            // 8 KB
    unsigned short* Bs = (unsigned short*)(smem + 8192);   // 8 KB
    const unsigned short* A = qp + (size_t)b * QLEN * 1024 + 512 + h * DKH;
    const unsigned short* B = kp + (size_t)b * KLEN * 1024 + 512 + h * DKH;
    const int bm = by * 128, bn = bx * 128;

    const int wv = tid >> 6, ln = tid & 63;
    const int r = ln & 15, quad = ln >> 4;
    const int wm = (wv >> 1) * 64, wn = (wv & 1) * 64;
    const int srow = (wv & 3) * 16 + (ln >> 2);
    const int scol = (ln & 3) * 8;

    f32x4 acc[4][4]; zero_acc(acc);
    for (int ks = 0; ks < 4; ++ks) {
        const int k0 = ks * 32;
        if (worker) {
            #pragma unroll
            for (int j = 0; j < 2; ++j) {
                gload_lds16(A + (size_t)(bm + j * 64 + srow) * 1024 + k0 + scol,
                            As + (size_t)(j * 64 + wv * 16) * 32);
                gload_lds16(B + (size_t)(bn + j * 64 + srow) * 1024 + k0 + scol,
                            Bs + (size_t)(j * 64 + wv * 16) * 32);
            }
        }
        __syncthreads();
        if (worker) {
            bf16x8 af[4], bg[4];
            #pragma unroll
            for (int f = 0; f < 4; ++f)
                af[f] = *(const bf16x8*)(As + (size_t)(wm + f * 16 + r) * 32 + quad * 8);
            #pragma unroll
            for (int f = 0; f < 4; ++f)
                bg[f] = *(const bf16x8*)(Bs + (size_t)(wn + f * 16 + r) * 32 + quad * 8);
            #pragma unroll
            for (int i = 0; i < 4; ++i)
                #pragma unroll
                for (int j2 = 0; j2 < 4; ++j2)
                    acc[i][j2] = __builtin_amdgcn_mfma_f32_16x16x32_bf16(
                        af[i], bg[j2], acc[i][j2], 0, 0, 0);
        }
        __syncthreads();
    }
    if (worker) {
        const int m0 = bm + (wv >> 1) * 64, n0 = bn + (wv & 1) * 64;
        #pragma unroll
        for (int i = 0; i < 4; ++i) {
            #pragma unroll
            for (int reg = 0; reg < 4; ++reg) {
                const int q = m0 + i * 16 + quad * 4 + reg;
                const size_t rowoff = ((size_t)z * QLEN + q) * KLEN;
                #pragma unroll
                for (int j = 0; j < 4; ++j) {
                    const int k = n0 + j * 16 + r;
                    out[rowoff + k] = acc[i][j][reg] * INV_SCALE;
                }
            }
        }
    }
}

// ---------------------------------------------------------------------------
// beta: per (b,h,q) row of 2048 (e_chunk in d_out, overwritten)
// ---------------------------------------------------------------------------
__global__ __launch_bounds__(256) void beta_kernel(
    float* __restrict__ eo, const float* __restrict__ alpha)
{
    __shared__ float sse[KLEN + 3];
    __shared__ float su[KLEN + 3];
    __shared__ float wmax[4];

    const int tid = threadIdx.x;
    const int lane = tid & 63, wid = tid >> 6;
    const int row = blockIdx.x;                 // [B*H*Q]
    const int q = row & (QLEN - 1);
    const int b = row >> 10;
    float* erow = eo + (size_t)row * KLEN;
    const float* arow = alpha + ((size_t)b * QLEN + q) * KLEN;

    if (tid < 3) { sse[tid] = 0.0f; su[KLEN + tid] = 0.0f; }

    float ev[8];
    float lm = -INFINITY;
    #pragma unroll
    for (int j = 0; j < 8; ++j) {
        const int k = tid + 256 * j;
        ev[j] = erow[k];
        lm = fmaxf(lm, ev[j]);
    }
    #pragma unroll
    for (int off = 32; off > 0; off >>= 1) lm = fmaxf(lm, __shfl_xor(lm, off));
    if (lane == 0) wmax[wid] = lm;
    __syncthreads();
    const float mx = fmaxf(fmaxf(wmax[0], wmax[1]), fmaxf(wmax[2], wmax[3]));

    #pragma unroll
    for (int j = 0; j < 8; ++j) {
        const int k = tid + 256 * j;
        sse[k + 3] = fmaxf(__expf(ev[j] - mx), 1e-5f);
    }
    __syncthreads();

    #pragma unroll
    for (int j = 0; j < 8; ++j) {
        const int k = tid + 256 * j;
        const float denom = sse[k + 3] + sse[k + 2] + sse[k + 1] + sse[k];
        su[k] = arow[k] * __builtin_amdgcn_rcpf(denom);
    }
    __syncthreads();

    #pragma unroll
    for (int j = 0; j < 8; ++j) {
        const int k = tid + 256 * j;
        erow[k] = sse[k + 3] * (su[k] + su[k + 1] + su[k + 2] + su[k + 3]);
    }
}

// ---------------------------------------------------------------------------
extern "C" void kernel_launch(void* const* d_in, const int* in_sizes, int n_in,
                              void* d_out, int out_size, void* d_ws, size_t ws_size,
                              hipStream_t stream)
{
    (void)in_sizes; (void)n_in; (void)out_size; (void)ws_size;
    const float* key_enc = (const float*)d_in[0];   // [8,2048,512]
    const float* query   = (const float*)d_in[1];   // [8,256,512]
    const float* noise   = (const float*)d_in[2];   // [8,256,2048]
    const float* Wk_m    = (const float*)d_in[3];
    const float* bk_m    = (const float*)d_in[4];
    const float* Wq_m    = (const float*)d_in[5];
    const float* bq_m    = (const float*)d_in[6];
    const float* rp      = (const float*)d_in[7];
    const float* Wk_c    = (const float*)d_in[8];
    const float* bk_c    = (const float*)d_in[9];
    const float* Wq_c    = (const float*)d_in[10];
    const float* bq_c    = (const float*)d_in[11];
    float* out = (float*)d_out;                     // [8,4,256,2048]

    // workspace layout (bytes)
    char* w = (char*)d_ws;
    unsigned short* kx    = (unsigned short*)w; w += (size_t)BATCH * KLEN * KDIM * 2;   // 16.8 MB
    unsigned short* qx    = (unsigned short*)w; w += (size_t)BATCH * QLEN * KDIM * 2;   //  2.1 MB
    unsigned short* WTk   = (unsigned short*)w; w += (size_t)1024 * KDIM * 2;           //  1.0 MB
    unsigned short* WTq   = (unsigned short*)w; w += (size_t)1024 * KDIM * 2;           //  1.0 MB
    unsigned short* kproj = (unsigned short*)w; w += (size_t)BATCH * KLEN * 1024 * 2;   // 33.6 MB
    unsigned short* qproj = (unsigned short*)w; w += (size_t)BATCH * QLEN * 1024 * 2;   //  4.2 MB
    float* p_alpha = (float*)w; w += (size_t)BATCH * QLEN * KLEN * 4;                   // 16.8 MB
    float* mArr    = (float*)w; w += (size_t)BATCH * QLEN * KLEN * 4;                   // 16.8 MB
    float* rArr    = (float*)w;                                                         // 16.8 MB

    // 1) casts
    hipLaunchKernelGGL(cast_bf16, dim3(BATCH * KLEN * KDIM / 4 / 256), dim3(256), 0, stream,
                       key_enc, kx, BATCH * KLEN * KDIM / 4);
    hipLaunchKernelGGL(cast_bf16, dim3(BATCH * QLEN * KDIM / 4 / 256), dim3(256), 0, stream,
                       query, qx, BATCH * QLEN * KDIM / 4);
    hipLaunchKernelGGL(transpose_cast, dim3(16, 16), dim3(32, 8), 0, stream, Wk_m, WTk);
    hipLaunchKernelGGL(transpose_cast, dim3(16, 16), dim3(32, 8), 0, stream, Wk_c, WTk + (size_t)512 * KDIM);
    hipLaunchKernelGGL(transpose_cast, dim3(16, 16), dim3(32, 8), 0, stream, Wq_m, WTq);
    hipLaunchKernelGGL(transpose_cast, dim3(16, 16), dim3(32, 8), 0, stream, Wq_c, WTq + (size_t)512 * KDIM);

    // 2) projections (staged bf16 MFMA, fused bias, bf16 out)
    hipLaunchKernelGGL(proj_mfma, dim3(8, BATCH * KLEN / 128), dim3(256), 0, stream,
                       kx, WTk, bk_m, bk_c, kproj);
    hipLaunchKernelGGL(proj_mfma, dim3(8, BATCH * QLEN / 128), dim3(256), 0, stream,
                       qx, WTq, bq_m, bq_c, qproj);

    // 3) p_choose (staged bf16 MFMA + fast sigmoid epilogue)
    hipLaunchKernelGGL(pchoose_mfma, dim3(KLEN / 128, QLEN / 128, BATCH), dim3(256), 0, stream,
                       qproj, kproj, noise, rp, p_alpha);

    // 4) cumprod -> (m, r)  (parallel, absorbs all transcendentals)
    hipLaunchKernelGGL(cumprod_mr, dim3(BATCH * QLEN), dim3(256), 0, stream,
                       p_alpha, mArr, rArr);

    // 5) FUSED: alpha recurrence (blocks 0..7) + e_chunk (blocks 8..1031)
    hipLaunchKernelGGL(alpha_echunk, dim3(BATCH + KLEN / 128 * QLEN / 128 * BATCH * NHEADS),
                       dim3(512), 0, stream,
                       mArr, rArr, p_alpha, qproj, kproj, out);

    // 6) beta (overwrites e_chunk rows in d_out)
    hipLaunchKernelGGL(beta_kernel, dim3(BATCH * NHEADS * QLEN), dim3(256), 0, stream,
                       out, p_alpha);
}